// Round 8
// baseline (1204.993 us; speedup 1.0000x reference)
//
#include <hip/hip_runtime.h>
#include <hip/hip_bf16.h>

typedef unsigned short u16;
typedef __attribute__((ext_vector_type(8))) short short8;
typedef __attribute__((ext_vector_type(4))) short short4v;
typedef __attribute__((ext_vector_type(4))) float floatx4;

__device__ __forceinline__ u16 f2bf(float x) {
  unsigned u = __float_as_uint(x);
  u += 0x7fffu + ((u >> 16) & 1u);           // round-to-nearest-even to bf16
  return (u16)(u >> 16);
}
__device__ __forceinline__ float bf2f(u16 u) {
  return __uint_as_float(((unsigned)u) << 16);
}
__device__ __forceinline__ float sigm(float x) {
  return 1.0f / (1.0f + __expf(-x));
}

// ---------------- prep kernels ----------------

// x1,x2: (B=4, T=8, 128, 32, 32) fp32 -> X: [slot=t*4+b][1024 pix][256 ch] bf16 hi/lo
__global__ __launch_bounds__(256) void xsplit_kernel(
    const float* __restrict__ x1, const float* __restrict__ x2,
    u16* __restrict__ Xh, u16* __restrict__ Xl)
{
  __shared__ float lds[128][65];
  int bx  = blockIdx.x;              // 1024 blocks
  int sel = bx >> 9;                 // 0: x1, 1: x2
  int rem = bx & 511;
  int bt  = rem >> 4;                // b*8+t (source layout order)
  int pg  = rem & 15;                // 64-pixel group
  int b = bt >> 3, t = bt & 7;
  int p0 = pg << 6;
  const float* src = (sel ? x2 : x1) + ((size_t)bt << 17);
  int tid = threadIdx.x;
  #pragma unroll
  for (int k2 = 0; k2 < 8; ++k2) {
    int idx = tid + (k2 << 8);
    int c = idx >> 4, p4 = (idx & 15) << 2;
    floatx4 v = *reinterpret_cast<const floatx4*>(src + ((size_t)c << 10) + p0 + p4);
    lds[c][p4] = v[0]; lds[c][p4 + 1] = v[1]; lds[c][p4 + 2] = v[2]; lds[c][p4 + 3] = v[3];
  }
  __syncthreads();
  int pl = tid >> 2;                 // pixel 0..63
  int cg = (tid & 3) << 5;           // channel group
  size_t obase = (((size_t)((t * 4 + b) * 1024 + p0 + pl)) << 8) + (sel << 7) + cg;
  #pragma unroll
  for (int q = 0; q < 4; ++q) {
    short8 hv, lv;
    #pragma unroll
    for (int j = 0; j < 8; ++j) {
      float f = lds[cg + q * 8 + j][pl];
      u16 h = f2bf(f);
      hv[j] = (short)h;
      lv[j] = (short)f2bf(f - bf2f(h));
    }
    *reinterpret_cast<short8*>(Xh + obase + q * 8) = hv;
    *reinterpret_cast<short8*>(Xl + obase + q * 8) = lv;
  }
}

// W: (512, CIN, 3, 3) fp32 -> packed frag layout, rows reordered n' = oc*4+gate:
// value(n',k), k=(ky*3+kx)*CIN+ci, stored at [(n'>>4)*(K/8)+(k>>3)][n'&15][k&7]
__global__ __launch_bounds__(256) void wsplit_kernel(
    const float* __restrict__ W, u16* __restrict__ Wh, u16* __restrict__ Wl, int CIN)
{
  int K = CIN * 9;
  int i = blockIdx.x * 256 + threadIdx.x;
  int np = i / K;
  int k = i - np * K;
  int e9 = k / CIN;
  int ci = k - e9 * CIN;
  int n = (np & 3) * 128 + (np >> 2);          // original row (gate*128 + oc)
  float v = W[((size_t)n * CIN + ci) * 9 + e9];
  size_t o = ((size_t)((np >> 4) * (K >> 3) + (k >> 3)) * 16 + (np & 15)) * 8 + (k & 7);
  u16 h = f2bf(v);
  Wh[o] = h;
  Wl[o] = f2bf(v - bf2f(h));
}

__global__ __launch_bounds__(256) void init_state(
    float* __restrict__ c1, float* __restrict__ c2, float* __restrict__ c3,
    u16* __restrict__ h1h, u16* __restrict__ h1l,
    u16* __restrict__ h2h, u16* __restrict__ h2l,
    u16* __restrict__ h3h, u16* __restrict__ h3l)
{
  int i = blockIdx.x * 256 + threadIdx.x;   // 524288
  c1[i] = 0.f; c2[i] = 0.f; c3[i] = 0.f;
  h1h[i] = 0; h1l[i] = 0; h2h[i] = 0; h2l[i] = 0; h3h[i] = 0; h3l[i] = 0;
}

// ---------------- conv as GEMM: halo-staged A, K-split, templated m-tile ----
// YR = y-rows per m-tile (m-tile = 32*YR pixels). Block (32*YR)m x 128n', 4 waves:
// wid = kh*2+nh; wave-tile (32*YR)m x 64n' at K-half kh. Halo (YR+2)x34 pixel-rows
// x 64ch (zero-padded, XOR-swizzled 128B rows) staged once per 64-ci chunk.
// B direct global->frag from packed W (256B bursts), 1-unit register pipeline.
// hi/lo split: acc += Ah*Wh + Ah*Wl + Al*Wh.
// Block order: nt = high bits of blockIdx (XCD-temporal W locality).
template<bool FUSE, int YR, int BPC>
__global__ __launch_bounds__(256, BPC) void conv_gemm(
    const u16* __restrict__ A1h, const u16* __restrict__ A1l, int CA,
    const u16* __restrict__ A2h, const u16* __restrict__ A2l, int CB,
    const u16* __restrict__ Wh, const u16* __restrict__ Wl,   // packed
    int WCIN, int wcoff, int WK, int MT,       // MT = number of m-tiles
    float* __restrict__ zout,                  // FUSE=false
    const float* __restrict__ zx,              // FUSE=true (optional)
    const float* __restrict__ bias,            // FUSE=true
    float* __restrict__ c, u16* __restrict__ hh, u16* __restrict__ hl,
    float* __restrict__ hout)
{
  constexpr int PROWS = (YR + 2) * 34;
  constexpr int HALOB = PROWS * 128;           // bytes per hi/lo array
  constexpr int MF = 2 * YR;                   // m-fragments of 16
  constexpr int RLD = (PROWS * 8 + 255) / 256; // staging iterations
  const int CIN = CA + CB;

  __shared__ __align__(16) char smem[2 * HALOB];

  int tid = threadIdx.x;
  int bx  = blockIdx.x;
  int nt = bx / MT;         // 0..3 (high bits: W-slice temporal locality)
  int mt = bx - nt * MT;
  int m0 = mt * (32 * YR);
  int slot = m0 >> 10;
  int pbase = m0 & 1023;
  int y0 = pbase >> 5;
  int n0 = nt * 128;

  int lane = tid & 63, wid = tid >> 6;
  int nh = wid & 1, kh = wid >> 1;
  int fr = lane & 15, kq = lane >> 4;
  const int WK8 = WK >> 3;
  const int g16b = (n0 >> 4) + nh * 4;

  floatx4 acc[MF][4];
  #pragma unroll
  for (int i2 = 0; i2 < MF; ++i2)
    #pragma unroll
    for (int j2 = 0; j2 < 4; ++j2)
      acc[i2][j2] = (floatx4)0.0f;

  short8 RH[RLD], RL[RLD];
  const int NC = CIN >> 6;

  auto ldA = [&](int cc) {
    const u16 *sh, *sl; int cbase, CH;
    if (cc < CA) { sh = A1h; sl = A1l; cbase = cc;      CH = CA; }
    else         { sh = A2h; sl = A2l; cbase = cc - CA; CH = CB; }
    #pragma unroll
    for (int r = 0; r < RLD; ++r) {
      int u = tid + 256 * r;
      if (u < PROWS * 8) {
        int prow = u >> 3, cq = u & 7;
        int hrow = prow / 34;
        int xcol = prow - hrow * 34;
        int y = y0 - 1 + hrow;
        int x = xcol - 1;
        bool valid = ((unsigned)y < 32u) & ((unsigned)x < 32u);
        short8 vh = (short8)0, vl = (short8)0;
        if (valid) {
          size_t ab = (size_t)(slot * 1024 + y * 32 + x) * CH + cbase + cq * 8;
          vh = *reinterpret_cast<const short8*>(sh + ab);
          vl = *reinterpret_cast<const short8*>(sl + ab);
        }
        RH[r] = vh; RL[r] = vl;
      }
    }
  };

  auto stA = [&]() {
    #pragma unroll
    for (int r = 0; r < RLD; ++r) {
      int u = tid + 256 * r;
      if (u < PROWS * 8) {
        int prow = u >> 3, cq = u & 7;
        int off = prow * 128 + (((cq ^ (prow & 7)) & 7) << 4);   // XOR swizzle
        *reinterpret_cast<short8*>(smem + off)         = RH[r];
        *reinterpret_cast<short8*>(smem + HALOB + off) = RL[r];
      }
    }
  };

  auto computeChunk = [&](int cc) {
    const int u0 = kh ? 9 : 0;           // K-half split over 18 (e9,ks) units
    short8 Bch[4], Bcl[4];
    {
      int kb = wcoff + (u0 >> 1) * WCIN + cc + (u0 & 1) * 32 + kq * 8;
      #pragma unroll
      for (int nf = 0; nf < 4; ++nf) {
        size_t bo = ((size_t)((g16b + nf) * WK8 + (kb >> 3)) * 16 + fr) * 8;
        Bch[nf] = *reinterpret_cast<const short8*>(Wh + bo);
        Bcl[nf] = *reinterpret_cast<const short8*>(Wl + bo);
      }
    }
    #pragma unroll 1
    for (int ui = 0; ui < 9; ++ui) {
      int u = u0 + ui;
      int e9 = u >> 1, ks = u & 1;
      short8 Bnh_[4], Bnl_[4];
      if (ui < 8) {                      // prefetch next unit's B
        int un = u + 1;
        int kb = wcoff + (un >> 1) * WCIN + cc + (un & 1) * 32 + kq * 8;
        #pragma unroll
        for (int nf = 0; nf < 4; ++nf) {
          size_t bo = ((size_t)((g16b + nf) * WK8 + (kb >> 3)) * 16 + fr) * 8;
          Bnh_[nf] = *reinterpret_cast<const short8*>(Wh + bo);
          Bnl_[nf] = *reinterpret_cast<const short8*>(Wl + bo);
        }
      }
      int dy = e9 / 3 - 1;
      int dx = e9 - (e9 / 3) * 3 - 1;
      short8 Ah_[MF], Al_[MF];
      #pragma unroll
      for (int mf = 0; mf < MF; ++mf) {
        int ar = mf * 16 + fr;           // tile pixel
        int prow = ((ar >> 5) + 1 + dy) * 34 + (ar & 31) + 1 + dx;
        int off = prow * 128 + ((((ks * 4 + kq) ^ (prow & 7)) & 7) << 4);
        Ah_[mf] = *reinterpret_cast<const short8*>(smem + off);
        Al_[mf] = *reinterpret_cast<const short8*>(smem + HALOB + off);
      }
      __builtin_amdgcn_s_setprio(1);
      #pragma unroll
      for (int mf = 0; mf < MF; ++mf)
        #pragma unroll
        for (int nf = 0; nf < 4; ++nf)
          acc[mf][nf] = __builtin_amdgcn_mfma_f32_16x16x32_bf16(Ah_[mf], Bch[nf], acc[mf][nf], 0, 0, 0);
      #pragma unroll
      for (int mf = 0; mf < MF; ++mf)
        #pragma unroll
        for (int nf = 0; nf < 4; ++nf)
          acc[mf][nf] = __builtin_amdgcn_mfma_f32_16x16x32_bf16(Ah_[mf], Bcl[nf], acc[mf][nf], 0, 0, 0);
      #pragma unroll
      for (int mf = 0; mf < MF; ++mf)
        #pragma unroll
        for (int nf = 0; nf < 4; ++nf)
          acc[mf][nf] = __builtin_amdgcn_mfma_f32_16x16x32_bf16(Al_[mf], Bch[nf], acc[mf][nf], 0, 0, 0);
      __builtin_amdgcn_s_setprio(0);
      if (ui < 8) {
        #pragma unroll
        for (int nf = 0; nf < 4; ++nf) { Bch[nf] = Bnh_[nf]; Bcl[nf] = Bnl_[nf]; }
      }
    }
  };

  // ---- main loop: stage halo once per ci-chunk, 2 barriers/chunk ----
  ldA(0); stA();
  for (int q = 0; q < NC; ++q) {
    if (q + 1 < NC) ldA((q + 1) << 6);
    __syncthreads();                     // stA(q) visible
    computeChunk(q << 6);
    __syncthreads();                     // all halo reads done
    if (q + 1 < NC) stA();
  }

  // ---- epilogue: kh-pair reduction in LDS ----
  float (*tr)[68] = reinterpret_cast<float(*)[68]>(smem + nh * HALOB);
  if (kh == 0) {
    #pragma unroll
    for (int mf = 0; mf < MF; ++mf)
      #pragma unroll
      for (int nf = 0; nf < 4; ++nf)
        #pragma unroll
        for (int r = 0; r < 4; ++r)
          tr[mf * 16 + kq * 4 + r][nf * 16 + fr] = acc[mf][nf][r];
  }
  __syncthreads();
  if (kh == 1) {
    #pragma unroll
    for (int mf = 0; mf < MF; ++mf)
      #pragma unroll
      for (int nf = 0; nf < 4; ++nf)
        #pragma unroll
        for (int r = 0; r < 4; ++r)
          tr[mf * 16 + kq * 4 + r][nf * 16 + fr] += acc[mf][nf][r];
  }
  __syncthreads();

  int m  = (YR == 1) ? (lane & 31) : lane;
  int ol = (YR == 1) ? (lane >> 5) : 0;
  int ppix = pbase + m;
  size_t grow = (size_t)slot * 1024 + ppix;

  if (!FUSE) {
    // z[m][n'] stores, each wave its K-half quarter columns
    size_t zrow = ((size_t)(m0 + m) << 9) + n0 + nh * 64 + kh * 32 + ol * 16;
    constexpr int NJ = (YR == 1) ? 4 : 8;
    #pragma unroll
    for (int j = 0; j < NJ; ++j) {
      floatx4 v = *reinterpret_cast<const floatx4*>(&tr[m][kh * 32 + ol * 16 + j * 4]);
      *reinterpret_cast<floatx4*>(zout + zrow + j * 4) = v;
    }
    return;
  }

  constexpr int NJ = (YR == 1) ? 4 : 8;
  int obc = kh * 8 + ol * 4;             // first oc (local to nh-half) this lane owns
  float cnv[NJ], hnv[NJ];
  #pragma unroll
  for (int j = 0; j < NJ; ++j) {
    int oc = obc + j;
    int ocg = nt * 32 + nh * 16 + oc;
    float zg[4];
    floatx4 tv = *reinterpret_cast<const floatx4*>(&tr[m][oc * 4]);
    if (zx) {
      floatx4 zv = *reinterpret_cast<const floatx4*>(zx + (grow << 9) + n0 + nh * 64 + oc * 4);
      #pragma unroll
      for (int g = 0; g < 4; ++g) zg[g] = tv[g] + zv[g] + bias[g * 128 + ocg];
    } else {
      #pragma unroll
      for (int g = 0; g < 4; ++g) zg[g] = tv[g] + bias[g * 128 + ocg];
    }
    size_t cidx = grow * 128 + ocg;
    float cvl = c[cidx];
    float cn = sigm(zg[1]) * cvl + sigm(zg[0]) * tanhf(zg[3]);
    float hn = sigm(zg[2]) * tanhf(cn);
    cnv[j] = cn; hnv[j] = hn;
    if (hout) hout[((size_t)slot * 128 + ocg) * 1024 + ppix] = hn;   // NCHW
  }
  size_t obase = grow * 128 + nt * 32 + nh * 16 + obc;
  if constexpr (YR == 1) {
    floatx4 cv; short4v hv, lv;
    #pragma unroll
    for (int j = 0; j < 4; ++j) {
      cv[j] = cnv[j];
      u16 hb = f2bf(hnv[j]);
      hv[j] = (short)hb;
      lv[j] = (short)f2bf(hnv[j] - bf2f(hb));
    }
    *reinterpret_cast<floatx4*>(c + obase) = cv;
    *reinterpret_cast<short4v*>(hh + obase) = hv;
    *reinterpret_cast<short4v*>(hl + obase) = lv;
  } else {
    floatx4 cv[2]; short8 hv, lv;
    #pragma unroll
    for (int j = 0; j < 8; ++j) {
      cv[j >> 2][j & 3] = cnv[j];
      u16 hb = f2bf(hnv[j]);
      hv[j] = (short)hb;
      lv[j] = (short)f2bf(hnv[j] - bf2f(hb));
    }
    *reinterpret_cast<floatx4*>(c + obase)     = cv[0];
    *reinterpret_cast<floatx4*>(c + obase + 4) = cv[1];
    *reinterpret_cast<short8*>(hh + obase) = hv;
    *reinterpret_cast<short8*>(hl + obase) = lv;
  }
}

extern "C" void kernel_launch(void* const* d_in, const int* in_sizes, int n_in,
                              void* d_out, int out_size, void* d_ws, size_t ws_size,
                              hipStream_t stream)
{
  const float* x1 = (const float*)d_in[0];
  const float* x2 = (const float*)d_in[1];
  const float* W1 = (const float*)d_in[2];
  const float* b1 = (const float*)d_in[3];
  const float* W2 = (const float*)d_in[4];
  const float* b2 = (const float*)d_in[5];
  const float* W3 = (const float*)d_in[6];
  const float* b3 = (const float*)d_in[7];
  float* out = (float*)d_out;

  char* ws = (char*)d_ws;
  size_t off = 0;
  auto alloc = [&](size_t bytes) {
    char* p = ws + off;
    off += (bytes + 255) & ~(size_t)255;
    return p;
  };
  u16*   Xh  = (u16*)  alloc(16777216);   // [32 slot][1024][256]
  u16*   Xl  = (u16*)  alloc(16777216);
  u16*   W1h = (u16*)  alloc(3538944);    // packed [32][432][16][8]
  u16*   W1l = (u16*)  alloc(3538944);
  u16*   W2h = (u16*)  alloc(2359296);    // packed [32][288][16][8]
  u16*   W2l = (u16*)  alloc(2359296);
  u16*   W3h = (u16*)  alloc(2359296);
  u16*   W3l = (u16*)  alloc(2359296);
  u16*   hb_[12];                         // h ping-pong: layer x {h,l} x parity
  for (int i = 0; i < 12; ++i) hb_[i] = (u16*)alloc(1048576);   // [4][1024][128]
  float* c1  = (float*)alloc(2097152);    // [4][1024][128] fp32
  float* c2  = (float*)alloc(2097152);
  float* c3  = (float*)alloc(2097152);
  float* zx  = (float*)alloc(67108864);   // [32 slot][1024][512] fp32
  if (off > ws_size) return;

  u16 **h1h = &hb_[0], **h1l = &hb_[2], **h2h = &hb_[4], **h2l = &hb_[6],
      **h3h = &hb_[8], **h3l = &hb_[10];

  xsplit_kernel<<<1024, 256, 0, stream>>>(x1, x2, Xh, Xl);
  wsplit_kernel<<<6912, 256, 0, stream>>>(W1, W1h, W1l, 384);
  wsplit_kernel<<<4608, 256, 0, stream>>>(W2, W2h, W2l, 256);
  wsplit_kernel<<<4608, 256, 0, stream>>>(W3, W3h, W3l, 256);
  init_state<<<2048, 256, 0, stream>>>(c1, c2, c3,
      hb_[0], hb_[2], hb_[4], hb_[6], hb_[8], hb_[10]);   // parity-0 buffers

  // big GEMM: L1 x-contribution for all T (M=32768, K=2304) -> zx[m][n']
  // YR=2 (64m tiles, MT=512), 3 blocks/CU
  conv_gemm<false, 2, 3><<<2048, 256, 0, stream>>>(
      Xh, Xl, 256, nullptr, nullptr, 0, W1h, W1l, 384, 0, 3456, 512,
      zx, nullptr, nullptr, nullptr, nullptr, nullptr, nullptr);

  // sequential convs: YR=1 (32m tiles, MT=128, grid 512 = 2 blocks/CU)
  for (int t = 0; t < 8; ++t) {
    int pi = t & 1, po = pi ^ 1;
    const float* zxt = zx + (size_t)t * 2097152;
    // layer 1: h-part (K=1152, W1 channels 256..383) + zx + gates -> h1,c1
    conv_gemm<true, 1, 2><<<512, 256, 0, stream>>>(
        h1h[pi], h1l[pi], 128, nullptr, nullptr, 0, W1h, W1l, 384, 256, 3456, 128,
        nullptr, zxt, b1, c1, h1h[po], h1l[po], nullptr);
    // layer 2: [h1_new, h2_old]
    conv_gemm<true, 1, 2><<<512, 256, 0, stream>>>(
        h1h[po], h1l[po], 128, h2h[pi], h2l[pi], 128, W2h, W2l, 256, 0, 2304, 128,
        nullptr, nullptr, b2, c2, h2h[po], h2l[po], nullptr);
    // layer 3: [h2_new, h3_old]
    conv_gemm<true, 1, 2><<<512, 256, 0, stream>>>(
        h2h[po], h2l[po], 128, h3h[pi], h3l[pi], 128, W3h, W3l, 256, 0, 2304, 128,
        nullptr, nullptr, b3, c3, h3h[po], h3l[po], (t == 7) ? out : nullptr);
  }
}

// Round 9
// 1047.986 us; speedup vs baseline: 1.1498x; 1.1498x over previous
//
#include <hip/hip_runtime.h>
#include <hip/hip_bf16.h>

typedef unsigned short u16;
typedef __attribute__((ext_vector_type(8))) short short8;
typedef __attribute__((ext_vector_type(4))) short short4v;
typedef __attribute__((ext_vector_type(4))) float floatx4;

__device__ __forceinline__ u16 f2bf(float x) {
  unsigned u = __float_as_uint(x);
  u += 0x7fffu + ((u >> 16) & 1u);           // round-to-nearest-even to bf16
  return (u16)(u >> 16);
}
__device__ __forceinline__ float bf2f(u16 u) {
  return __uint_as_float(((unsigned)u) << 16);
}
__device__ __forceinline__ float sigm(float x) {
  return 1.0f / (1.0f + __expf(-x));
}

// ---------------- prep kernels ----------------

// x1,x2: (B=4, T=8, 128, 32, 32) fp32 -> X: [slot=t*4+b][1024 pix][256 ch] bf16 hi/lo
__global__ __launch_bounds__(256) void xsplit_kernel(
    const float* __restrict__ x1, const float* __restrict__ x2,
    u16* __restrict__ Xh, u16* __restrict__ Xl)
{
  __shared__ float lds[128][65];
  int bx  = blockIdx.x;              // 1024 blocks
  int sel = bx >> 9;                 // 0: x1, 1: x2
  int rem = bx & 511;
  int bt  = rem >> 4;                // b*8+t (source layout order)
  int pg  = rem & 15;                // 64-pixel group
  int b = bt >> 3, t = bt & 7;
  int p0 = pg << 6;
  const float* src = (sel ? x2 : x1) + ((size_t)bt << 17);
  int tid = threadIdx.x;
  #pragma unroll
  for (int k2 = 0; k2 < 8; ++k2) {
    int idx = tid + (k2 << 8);
    int c = idx >> 4, p4 = (idx & 15) << 2;
    floatx4 v = *reinterpret_cast<const floatx4*>(src + ((size_t)c << 10) + p0 + p4);
    lds[c][p4] = v[0]; lds[c][p4 + 1] = v[1]; lds[c][p4 + 2] = v[2]; lds[c][p4 + 3] = v[3];
  }
  __syncthreads();
  int pl = tid >> 2;                 // pixel 0..63
  int cg = (tid & 3) << 5;           // channel group
  size_t obase = (((size_t)((t * 4 + b) * 1024 + p0 + pl)) << 8) + (sel << 7) + cg;
  #pragma unroll
  for (int q = 0; q < 4; ++q) {
    short8 hv, lv;
    #pragma unroll
    for (int j = 0; j < 8; ++j) {
      float f = lds[cg + q * 8 + j][pl];
      u16 h = f2bf(f);
      hv[j] = (short)h;
      lv[j] = (short)f2bf(f - bf2f(h));
    }
    *reinterpret_cast<short8*>(Xh + obase + q * 8) = hv;
    *reinterpret_cast<short8*>(Xl + obase + q * 8) = lv;
  }
}

// W: (512, CIN, 3, 3) fp32 -> packed frag layout, rows reordered n' = oc*4+gate:
// value(n',k), k=(ky*3+kx)*CIN+ci, stored at [(n'>>4)*(K/8)+(k>>3)][n'&15][k&7]
__global__ __launch_bounds__(256) void wsplit_kernel(
    const float* __restrict__ W, u16* __restrict__ Wh, u16* __restrict__ Wl, int CIN)
{
  int K = CIN * 9;
  int i = blockIdx.x * 256 + threadIdx.x;
  int np = i / K;
  int k = i - np * K;
  int e9 = k / CIN;
  int ci = k - e9 * CIN;
  int n = (np & 3) * 128 + (np >> 2);          // original row (gate*128 + oc)
  float v = W[((size_t)n * CIN + ci) * 9 + e9];
  size_t o = ((size_t)((np >> 4) * (K >> 3) + (k >> 3)) * 16 + (np & 15)) * 8 + (k & 7);
  u16 h = f2bf(v);
  Wh[o] = h;
  Wl[o] = f2bf(v - bf2f(h));
}

__global__ __launch_bounds__(256) void init_state(
    float* __restrict__ c1, float* __restrict__ c2, float* __restrict__ c3,
    u16* __restrict__ h1h, u16* __restrict__ h1l,
    u16* __restrict__ h2h, u16* __restrict__ h2l,
    u16* __restrict__ h3h, u16* __restrict__ h3l)
{
  int i = blockIdx.x * 256 + threadIdx.x;   // 524288
  c1[i] = 0.f; c2[i] = 0.f; c3[i] = 0.f;
  h1h[i] = 0; h1l[i] = 0; h2h[i] = 0; h2l[i] = 0; h3h[i] = 0; h3l[i] = 0;
}

// ---------------- conv as GEMM: halo-staged A, K-split, templated m-tile ----
// YR = y-rows per m-tile; block (32*YR)m x 128n', 4 waves (wid = kh*2+nh);
// wave-tile (32*YR)m x 64n' at K-half kh. Halo (YR+2)x34 pixel-rows x 64ch
// (zero-padded, XOR-swizzled 128B rows) staged once per 64-ci chunk.
// B direct global->frag from packed W (256B bursts), DEPTH-unit reg pipeline
// (fully unrolled 9-unit loop -> all buffer indices static, no scratch).
// hi/lo split: acc += Ah*Wh + Ah*Wl + Al*Wh.
// XCD mapping: nt = (bx&7)>>1 -> blocks sharing a W n'-slice land on one XCD pair.
template<bool FUSE, int YR, int BPC, int DEPTH>
__global__ __launch_bounds__(256, BPC) void conv_gemm(
    const u16* __restrict__ A1h, const u16* __restrict__ A1l, int CA,
    const u16* __restrict__ A2h, const u16* __restrict__ A2l, int CB,
    const u16* __restrict__ Wh, const u16* __restrict__ Wl,   // packed
    int WCIN, int wcoff, int WK,
    float* __restrict__ zout,                  // FUSE=false
    const float* __restrict__ zx,              // FUSE=true (optional)
    const float* __restrict__ bias,            // FUSE=true
    float* __restrict__ c, u16* __restrict__ hh, u16* __restrict__ hl,
    float* __restrict__ hout)
{
  constexpr int PROWS = (YR + 2) * 34;
  constexpr int HALOB = PROWS * 128;           // bytes per hi/lo array
  constexpr int MF = 2 * YR;                   // m-fragments of 16
  constexpr int RLD = (PROWS * 8 + 255) / 256; // staging iterations
  const int CIN = CA + CB;

  __shared__ __align__(16) char smem[2 * HALOB];

  int tid = threadIdx.x;
  int bx  = blockIdx.x;
  int nt = (bx & 7) >> 1;               // XCD-pair-local W slice
  int mt = ((bx >> 3) << 1) | (bx & 1); // bijective m-tile index
  int m0 = mt * (32 * YR);
  int slot = m0 >> 10;
  int pbase = m0 & 1023;
  int y0 = pbase >> 5;
  int n0 = nt * 128;

  int lane = tid & 63, wid = tid >> 6;
  int nh = wid & 1, kh = wid >> 1;
  int fr = lane & 15, kq = lane >> 4;
  const int WK8 = WK >> 3;
  const int g16b = (n0 >> 4) + nh * 4;

  floatx4 acc[MF][4];
  #pragma unroll
  for (int i2 = 0; i2 < MF; ++i2)
    #pragma unroll
    for (int j2 = 0; j2 < 4; ++j2)
      acc[i2][j2] = (floatx4)0.0f;

  short8 RH[RLD], RL[RLD];
  const int NC = CIN >> 6;

  auto ldA = [&](int cc) {
    const u16 *sh, *sl; int cbase, CH;
    if (cc < CA) { sh = A1h; sl = A1l; cbase = cc;      CH = CA; }
    else         { sh = A2h; sl = A2l; cbase = cc - CA; CH = CB; }
    #pragma unroll
    for (int r = 0; r < RLD; ++r) {
      int u = tid + 256 * r;
      if (u < PROWS * 8) {
        int prow = u >> 3, cq = u & 7;
        int hrow = prow / 34;
        int xcol = prow - hrow * 34;
        int y = y0 - 1 + hrow;
        int x = xcol - 1;
        bool valid = ((unsigned)y < 32u) & ((unsigned)x < 32u);
        short8 vh = (short8)0, vl = (short8)0;
        if (valid) {
          size_t ab = (size_t)(slot * 1024 + y * 32 + x) * CH + cbase + cq * 8;
          vh = *reinterpret_cast<const short8*>(sh + ab);
          vl = *reinterpret_cast<const short8*>(sl + ab);
        }
        RH[r] = vh; RL[r] = vl;
      }
    }
  };

  auto stA = [&]() {
    #pragma unroll
    for (int r = 0; r < RLD; ++r) {
      int u = tid + 256 * r;
      if (u < PROWS * 8) {
        int prow = u >> 3, cq = u & 7;
        int off = prow * 128 + (((cq ^ (prow & 7)) & 7) << 4);   // XOR swizzle
        *reinterpret_cast<short8*>(smem + off)         = RH[r];
        *reinterpret_cast<short8*>(smem + HALOB + off) = RL[r];
      }
    }
  };

  auto computeChunk = [&](int cc) {
    const int u0 = kh ? 9 : 0;            // K-half split over 18 (e9,ks) units
    short8 Bh_[9 + DEPTH][4], Bl_[9 + DEPTH][4];   // static-indexed after unroll
    #pragma unroll
    for (int d = 0; d < DEPTH; ++d) {
      int kb = wcoff + ((u0 + d) >> 1) * WCIN + cc + ((u0 + d) & 1) * 32 + kq * 8;
      #pragma unroll
      for (int nf = 0; nf < 4; ++nf) {
        size_t bo = ((size_t)((g16b + nf) * WK8 + (kb >> 3)) * 16 + fr) * 8;
        Bh_[d][nf] = *reinterpret_cast<const short8*>(Wh + bo);
        Bl_[d][nf] = *reinterpret_cast<const short8*>(Wl + bo);
      }
    }
    #pragma unroll
    for (int ui = 0; ui < 9; ++ui) {
      if (ui + DEPTH < 9) {               // prefetch DEPTH units ahead
        int un = u0 + ui + DEPTH;
        int kb = wcoff + (un >> 1) * WCIN + cc + (un & 1) * 32 + kq * 8;
        #pragma unroll
        for (int nf = 0; nf < 4; ++nf) {
          size_t bo = ((size_t)((g16b + nf) * WK8 + (kb >> 3)) * 16 + fr) * 8;
          Bh_[ui + DEPTH][nf] = *reinterpret_cast<const short8*>(Wh + bo);
          Bl_[ui + DEPTH][nf] = *reinterpret_cast<const short8*>(Wl + bo);
        }
      }
      int u = u0 + ui;
      int e9 = u >> 1, ks = u & 1;
      int dy = e9 / 3 - 1;
      int dx = e9 - (e9 / 3) * 3 - 1;
      short8 Ah_[MF], Al_[MF];
      #pragma unroll
      for (int mf = 0; mf < MF; ++mf) {
        int ar = mf * 16 + fr;            // tile pixel
        int prow = ((ar >> 5) + 1 + dy) * 34 + (ar & 31) + 1 + dx;
        int off = prow * 128 + ((((ks * 4 + kq) ^ (prow & 7)) & 7) << 4);
        Ah_[mf] = *reinterpret_cast<const short8*>(smem + off);
        Al_[mf] = *reinterpret_cast<const short8*>(smem + HALOB + off);
      }
      __builtin_amdgcn_s_setprio(1);
      #pragma unroll
      for (int mf = 0; mf < MF; ++mf)
        #pragma unroll
        for (int nf = 0; nf < 4; ++nf)
          acc[mf][nf] = __builtin_amdgcn_mfma_f32_16x16x32_bf16(Ah_[mf], Bh_[ui][nf], acc[mf][nf], 0, 0, 0);
      #pragma unroll
      for (int mf = 0; mf < MF; ++mf)
        #pragma unroll
        for (int nf = 0; nf < 4; ++nf)
          acc[mf][nf] = __builtin_amdgcn_mfma_f32_16x16x32_bf16(Ah_[mf], Bl_[ui][nf], acc[mf][nf], 0, 0, 0);
      #pragma unroll
      for (int mf = 0; mf < MF; ++mf)
        #pragma unroll
        for (int nf = 0; nf < 4; ++nf)
          acc[mf][nf] = __builtin_amdgcn_mfma_f32_16x16x32_bf16(Al_[mf], Bh_[ui][nf], acc[mf][nf], 0, 0, 0);
      __builtin_amdgcn_s_setprio(0);
    }
  };

  // ---- main loop: stage halo once per ci-chunk, 2 barriers/chunk ----
  ldA(0); stA();
  for (int q = 0; q < NC; ++q) {
    if (q + 1 < NC) ldA((q + 1) << 6);
    __syncthreads();                     // stA(q) visible
    computeChunk(q << 6);
    __syncthreads();                     // all halo reads done
    if (q + 1 < NC) stA();
  }

  // ---- epilogue: kh-pair reduction in LDS ----
  float (*tr)[68] = reinterpret_cast<float(*)[68]>(smem + nh * HALOB);
  if (kh == 0) {
    #pragma unroll
    for (int mf = 0; mf < MF; ++mf)
      #pragma unroll
      for (int nf = 0; nf < 4; ++nf)
        #pragma unroll
        for (int r = 0; r < 4; ++r)
          tr[mf * 16 + kq * 4 + r][nf * 16 + fr] = acc[mf][nf][r];
  }
  __syncthreads();
  if (kh == 1) {
    #pragma unroll
    for (int mf = 0; mf < MF; ++mf)
      #pragma unroll
      for (int nf = 0; nf < 4; ++nf)
        #pragma unroll
        for (int r = 0; r < 4; ++r)
          tr[mf * 16 + kq * 4 + r][nf * 16 + fr] += acc[mf][nf][r];
  }
  __syncthreads();

  int m  = (YR == 1) ? (lane & 31) : lane;
  int ol = (YR == 1) ? (lane >> 5) : 0;
  int ppix = pbase + m;
  size_t grow = (size_t)slot * 1024 + ppix;

  if (!FUSE) {
    size_t zrow = ((size_t)(m0 + m) << 9) + n0 + nh * 64 + kh * 32 + ol * 16;
    constexpr int NJ = (YR == 1) ? 4 : 8;
    #pragma unroll
    for (int j = 0; j < NJ; ++j) {
      floatx4 v = *reinterpret_cast<const floatx4*>(&tr[m][kh * 32 + ol * 16 + j * 4]);
      *reinterpret_cast<floatx4*>(zout + zrow + j * 4) = v;
    }
    return;
  }

  constexpr int NJ = (YR == 1) ? 4 : 8;
  int obc = kh * 8 + ol * 4;             // first oc (local to nh-half) this lane owns
  float cnv[NJ], hnv[NJ];
  #pragma unroll
  for (int j = 0; j < NJ; ++j) {
    int oc = obc + j;
    int ocg = nt * 32 + nh * 16 + oc;
    float zg[4];
    floatx4 tv = *reinterpret_cast<const floatx4*>(&tr[m][oc * 4]);
    if (zx) {
      floatx4 zv = *reinterpret_cast<const floatx4*>(zx + (grow << 9) + n0 + nh * 64 + oc * 4);
      #pragma unroll
      for (int g = 0; g < 4; ++g) zg[g] = tv[g] + zv[g] + bias[g * 128 + ocg];
    } else {
      #pragma unroll
      for (int g = 0; g < 4; ++g) zg[g] = tv[g] + bias[g * 128 + ocg];
    }
    size_t cidx = grow * 128 + ocg;
    float cvl = c[cidx];
    float cn = sigm(zg[1]) * cvl + sigm(zg[0]) * tanhf(zg[3]);
    float hn = sigm(zg[2]) * tanhf(cn);
    cnv[j] = cn; hnv[j] = hn;
    if (hout) hout[((size_t)slot * 128 + ocg) * 1024 + ppix] = hn;   // NCHW
  }
  size_t obase = grow * 128 + nt * 32 + nh * 16 + obc;
  if constexpr (YR == 1) {
    floatx4 cv; short4v hv, lv;
    #pragma unroll
    for (int j = 0; j < 4; ++j) {
      cv[j] = cnv[j];
      u16 hb = f2bf(hnv[j]);
      hv[j] = (short)hb;
      lv[j] = (short)f2bf(hnv[j] - bf2f(hb));
    }
    *reinterpret_cast<floatx4*>(c + obase) = cv;
    *reinterpret_cast<short4v*>(hh + obase) = hv;
    *reinterpret_cast<short4v*>(hl + obase) = lv;
  } else {
    floatx4 cv[2]; short8 hv, lv;
    #pragma unroll
    for (int j = 0; j < 8; ++j) {
      cv[j >> 2][j & 3] = cnv[j];
      u16 hb = f2bf(hnv[j]);
      hv[j] = (short)hb;
      lv[j] = (short)f2bf(hnv[j] - bf2f(hb));
    }
    *reinterpret_cast<floatx4*>(c + obase)     = cv[0];
    *reinterpret_cast<floatx4*>(c + obase + 4) = cv[1];
    *reinterpret_cast<short8*>(hh + obase) = hv;
    *reinterpret_cast<short8*>(hl + obase) = lv;
  }
}

extern "C" void kernel_launch(void* const* d_in, const int* in_sizes, int n_in,
                              void* d_out, int out_size, void* d_ws, size_t ws_size,
                              hipStream_t stream)
{
  const float* x1 = (const float*)d_in[0];
  const float* x2 = (const float*)d_in[1];
  const float* W1 = (const float*)d_in[2];
  const float* b1 = (const float*)d_in[3];
  const float* W2 = (const float*)d_in[4];
  const float* b2 = (const float*)d_in[5];
  const float* W3 = (const float*)d_in[6];
  const float* b3 = (const float*)d_in[7];
  float* out = (float*)d_out;

  char* ws = (char*)d_ws;
  size_t off = 0;
  auto alloc = [&](size_t bytes) {
    char* p = ws + off;
    off += (bytes + 255) & ~(size_t)255;
    return p;
  };
  u16*   Xh  = (u16*)  alloc(16777216);   // [32 slot][1024][256]
  u16*   Xl  = (u16*)  alloc(16777216);
  u16*   W1h = (u16*)  alloc(3538944);    // packed [32][432][16][8]
  u16*   W1l = (u16*)  alloc(3538944);
  u16*   W2h = (u16*)  alloc(2359296);    // packed [32][288][16][8]
  u16*   W2l = (u16*)  alloc(2359296);
  u16*   W3h = (u16*)  alloc(2359296);
  u16*   W3l = (u16*)  alloc(2359296);
  u16*   hb_[12];                         // h ping-pong: layer x {h,l} x parity
  for (int i = 0; i < 12; ++i) hb_[i] = (u16*)alloc(1048576);   // [4][1024][128]
  float* c1  = (float*)alloc(2097152);    // [4][1024][128] fp32
  float* c2  = (float*)alloc(2097152);
  float* c3  = (float*)alloc(2097152);
  float* zx  = (float*)alloc(67108864);   // [32 slot][1024][512] fp32
  if (off > ws_size) return;

  u16 **h1h = &hb_[0], **h1l = &hb_[2], **h2h = &hb_[4], **h2l = &hb_[6],
      **h3h = &hb_[8], **h3l = &hb_[10];

  xsplit_kernel<<<1024, 256, 0, stream>>>(x1, x2, Xh, Xl);
  wsplit_kernel<<<6912, 256, 0, stream>>>(W1, W1h, W1l, 384);
  wsplit_kernel<<<4608, 256, 0, stream>>>(W2, W2h, W2l, 256);
  wsplit_kernel<<<4608, 256, 0, stream>>>(W3, W3h, W3l, 256);
  init_state<<<2048, 256, 0, stream>>>(c1, c2, c3,
      hb_[0], hb_[2], hb_[4], hb_[6], hb_[8], hb_[10]);   // parity-0 buffers

  // big GEMM: L1 x-contribution for all T (M=32768, K=2304) -> zx[m][n']
  // YR=2 (64m tiles), BPC=2 (R7 config: no spill), DEPTH=1
  conv_gemm<false, 2, 2, 1><<<2048, 256, 0, stream>>>(
      Xh, Xl, 256, nullptr, nullptr, 0, W1h, W1l, 384, 0, 3456,
      zx, nullptr, nullptr, nullptr, nullptr, nullptr, nullptr);

  // sequential convs: YR=1 (32m tiles, grid 512 = 2 blocks/CU), DEPTH=2
  for (int t = 0; t < 8; ++t) {
    int pi = t & 1, po = pi ^ 1;
    const float* zxt = zx + (size_t)t * 2097152;
    // layer 1: h-part (K=1152, W1 channels 256..383) + zx + gates -> h1,c1
    conv_gemm<true, 1, 2, 2><<<512, 256, 0, stream>>>(
        h1h[pi], h1l[pi], 128, nullptr, nullptr, 0, W1h, W1l, 384, 256, 3456,
        nullptr, zxt, b1, c1, h1h[po], h1l[po], nullptr);
    // layer 2: [h1_new, h2_old]
    conv_gemm<true, 1, 2, 2><<<512, 256, 0, stream>>>(
        h1h[po], h1l[po], 128, h2h[pi], h2l[pi], 128, W2h, W2l, 256, 0, 2304,
        nullptr, nullptr, b2, c2, h2h[po], h2l[po], nullptr);
    // layer 3: [h2_new, h3_old]
    conv_gemm<true, 1, 2, 2><<<512, 256, 0, stream>>>(
        h2h[po], h2l[po], 128, h3h[pi], h3l[pi], 128, W3h, W3l, 256, 0, 2304,
        nullptr, nullptr, b3, c3, h3h[po], h3l[po], (t == 7) ? out : nullptr);
  }
}